// Round 6
// baseline (337.816 us; speedup 1.0000x reference)
//
#include <hip/hip_runtime.h>

#define NT 512
#define SEASN 24

constexpr int SEA_STRIDE = NT + SEASN;   // 536
constexpr int LOG_STRIDE = NT - 1;       // 511
constexpr float LN2 = 0.6931471805599453f;

__device__ __forceinline__ float frcp(float x)  { return __builtin_amdgcn_rcpf(x); }
__device__ __forceinline__ float flog2(float x) { return __builtin_amdgcn_logf(x); }

// One wave = 2 series (lanes 0-23 and 32-55 active). The t%24 seasonal lag makes
// every 24-step window a constant-coefficient linear recurrence in lev:
//   lev_t = A*lev_{t-1} + c_t,  A = 1-a,  c_t = a*y_t/seas_t  (seas known in-window)
// -> Hillis-Steele scan over (P,Q) pairs, 5 shfl steps. Lane i owns pos=(1+i)%24
// forever, so the seasonal buffer is one register per lane, zero communication.
// RULE: every __shfl is issued unconditionally (all 64 lanes active) — a shfl
// inside a ternary/branch reads from EXEC-masked lanes => undefined (R5 bug).
__global__ __launch_bounds__(256)
void es_fwd(const float* __restrict__ y, const int* __restrict__ idxs,
            const float* __restrict__ lev_sms_p, const float* __restrict__ init_seas_p,
            float* __restrict__ levels, float* __restrict__ seasv,
            float* __restrict__ logd)
{
    const int tid  = threadIdx.x;
    const int lane = tid & 63;
    const int li   = lane & 31;          // index within series-group
    const int g    = lane >> 5;          // which series of this wave
    const int wv   = tid >> 6;
    const int srow = blockIdx.x * 8 + wv * 2 + g;

    const size_t yrow = (size_t)srow * NT;
    const int idx = idxs[srow];
    const float a = frcp(1.0f + __expf(-lev_sms_p[idx]));   // sigmoid; seas_sms==lev_sms (ref sic)
    const float A = 1.0f - a;

    const int p = (1 + li) % SEASN;      // this lane's fixed seasonal slot (valid for li<24)
    float sreg = 1.0f;
    if (li < 24) sreg = __expf(init_seas_p[(size_t)idx * SEASN + p]);

    const float is0 = init_seas_p[(size_t)idx * SEASN];
    float lev  = y[yrow] * frcp(__expf(is0));               // lev0 = y0 / init_seas0
    float glev = flog2(lev);                                // log2(lev_in) for window 0

    float* lrow = levels + (size_t)srow * NT;
    float* vrow = seasv  + (size_t)srow * SEA_STRIDE;
    float* drow = logd   + (size_t)srow * LOG_STRIDE;

    // init columns: levels[:,0]; seasv cols 0..23 = exp(init_seas); col 24 = exp(is[0])
    if (li == 0) lrow[0] = lev;
    if (li < 24) {
        vrow[p] = sreg;
        if (li == 23) vrow[24] = sreg;   // lane 23 holds pos 0
    }

    float ycur = (li < 24) ? y[yrow + 1 + li] : 1.0f;       // window 0: t = 1+li

    // 21 full windows of 24 steps (t=1..504) + tail of 7 (t=505..511)
    for (int w = 0; w < 22; ++w) {
        const int W = (w < 21) ? 24 : 7;

        // prefetch next window's y early (latency hides under the scan)
        float ynext = 1.0f;
        if (w < 21) {
            const int Wn = (w + 1 < 21) ? 24 : 7;
            if (li < Wn) ynext = y[yrow + 1 + 24 * (w + 1) + li];
        }

        // per-lane window input
        const float c = a * ycur * frcp(sreg);

        // inclusive scan: lane i ends with P=A^{i+1}, Q=sum_j A^{i-j} c_j
        float P = A, Q = c;
        #pragma unroll
        for (int d = 1; d < 32; d <<= 1) {
            const float Pp = __shfl(P, lane - d);            // unconditional shfl
            const float Qp = __shfl(Q, lane - d);
            if (li >= d) { Q += P * Qp; P *= Pp; }           // compose, stays in-group
        }
        const float nl = P * lev + Q;                         // lev at t = 1+24w+li
        const float ns = a * ycur * frcp(nl) + A * sreg;      // new season at this t
        const float gv = flog2(nl);
        const float gsh = __shfl(gv, lane - 1);               // unconditional (R5 fix)
        const float gp  = (li == 0) ? glev : gsh;

        if (li < W) {
            const int t = 1 + 24 * w + li;
            lrow[t]      = nl;                                // levels col t
            vrow[t + 24] = ns;                                // seasonalities col t+24
            drow[t - 1]  = (gv - gp) * LN2;                   // log-diff col t-1
            sreg = ns;                                        // buf[pos] update stays in-lane
        }
        lev  = __shfl(nl, (g << 5) + (W - 1));                // carry to next window
        glev = __shfl(gv, (g << 5) + (W - 1));
        ycur = ynext;
    }
}

extern "C" void kernel_launch(void* const* d_in, const int* in_sizes, int n_in,
                              void* d_out, int out_size, void* d_ws, size_t ws_size,
                              hipStream_t stream)
{
    const float* y         = (const float*)d_in[0];
    const int*   idxs      = (const int*)d_in[1];
    const float* lev_sms   = (const float*)d_in[2];
    // d_in[3] (seas_sms) unused: reference derives both smoothings from lev_sms_p
    const float* init_seas = (const float*)d_in[4];
    const int n_series = in_sizes[1];

    float* levels = (float*)d_out;
    float* seasv  = levels + (size_t)n_series * NT;
    float* logdv  = seasv  + (size_t)n_series * SEA_STRIDE;

    // 8 series per 256-thread block (2 per wave) -> 4096 blocks, no LDS, no barriers
    es_fwd<<<n_series / 8, 256, 0, stream>>>(y, idxs, lev_sms, init_seas,
                                             levels, seasv, logdv);
}

// Round 7
// 329.212 us; speedup vs baseline: 1.0261x; 1.0261x over previous
//
#include <hip/hip_runtime.h>

#define NT 512
#define SEASN 24

constexpr int SEA_STRIDE = NT + SEASN;   // 536
constexpr int LOG_STRIDE = NT - 1;       // 511
constexpr float LN2 = 0.6931471805599453f;

__device__ __forceinline__ float frcp(float x)  { return __builtin_amdgcn_rcpf(x); }
__device__ __forceinline__ float flog2(float x) { return __builtin_amdgcn_logf(x); }
__device__ __forceinline__ float bperm(int addr, float x) {
    return __int_as_float(__builtin_amdgcn_ds_bpermute(addr, __float_as_int(x)));
}

// One wave = 2 series (lanes 0-23 / 32-55 active). The t%24 seasonal lag makes each
// 24-step window a constant-coefficient linear recurrence lev_t = A*lev_{t-1} + c_t
// (A = 1-a, c_t = a*y_t/seas_t, seasons known in-window) -> suffix-scan with
// LANE-CONSTANT multipliers: step d composes Q += A^d * Q_{lane-d}. A^d is a scalar
// and the li>=d guard folds into per-lane constants m_d, so the inner scan is just
// 5 x {ds_bpermute + fma}. Final lev_i = A^(li+1)*lev_in + Q, A^(li+1) precomputed.
// RULE (R5): every bpermute is issued unconditionally (all 64 lanes active).
__global__ __launch_bounds__(256)
void es_fwd(const float* __restrict__ y, const int* __restrict__ idxs,
            const float* __restrict__ lev_sms_p, const float* __restrict__ init_seas_p,
            float* __restrict__ levels, float* __restrict__ seasv,
            float* __restrict__ logd)
{
    const int tid  = threadIdx.x;
    const int lane = tid & 63;
    const int li   = lane & 31;          // index within series-group
    const int gsel = lane & 32;          // 0 / 32: which series of this wave
    const int srow = blockIdx.x * 8 + (tid >> 6) * 2 + (gsel >> 5);

    const size_t yrow = (size_t)srow * NT;
    const int idx = idxs[srow];
    const float a = frcp(1.0f + __expf(-lev_sms_p[idx]));   // sigmoid; seas_sms==lev_sms (ref sic)
    const float A = 1.0f - a;

    // ---- once-per-kernel lane constants (hoisted out of the window loop) ----
    const int ad1  = ((lane - 1)  & 63) << 2;    // bpermute byte addrs
    const int ad2  = ((lane - 2)  & 63) << 2;
    const int ad4  = ((lane - 4)  & 63) << 2;
    const int ad8  = ((lane - 8)  & 63) << 2;
    const int ad16 = ((lane - 16) & 63) << 2;
    const int adc  = (gsel + 23) << 2;           // carry broadcast: lane 23 of own group

    const float A2 = A * A, A4 = A2 * A2, A8 = A4 * A4, A16 = A8 * A8;
    const float m1  = (li >= 1)  ? A   : 0.0f;   // guarded scan multipliers
    const float m2  = (li >= 2)  ? A2  : 0.0f;
    const float m4  = (li >= 4)  ? A4  : 0.0f;
    const float m8  = (li >= 8)  ? A8  : 0.0f;
    const float m16 = (li >= 16) ? A16 : 0.0f;
    const int e = li + 1;                        // propagator P = A^(li+1), binary powers
    float Pl = (e & 1) ? A : 1.0f;
    Pl *= (e & 2)  ? A2  : 1.0f;
    Pl *= (e & 4)  ? A4  : 1.0f;
    Pl *= (e & 8)  ? A8  : 1.0f;
    Pl *= (e & 16) ? A16 : 1.0f;

    const int p = (1 + li) % SEASN;      // this lane's fixed seasonal slot (li<24)
    float sreg = 1.0f;
    if (li < 24) sreg = __expf(init_seas_p[(size_t)idx * SEASN + p]);

    const float is0 = init_seas_p[(size_t)idx * SEASN];
    float lev  = y[yrow] * frcp(__expf(is0));    // lev0 = y0 / init_seas0 (broadcast load)
    float glev = flog2(lev);

    float* lrow = levels + (size_t)srow * NT;
    float* vrow = seasv  + (size_t)srow * SEA_STRIDE;
    float* drow = logd   + (size_t)srow * LOG_STRIDE;

    // init columns: levels[:,0]; seasv cols 0..23 = exp(init_seas); col 24 = exp(is[0])
    if (li == 0) lrow[0] = lev;
    if (li < 24) {
        vrow[p] = sreg;
        if (li == 23) vrow[24] = sreg;   // lane 23 holds pos 0
    }

    float ycur = (li < 24) ? y[yrow + 1 + li] : 1.0f;       // window 0: t = 1+li

    // ---- 21 full windows of 24 steps (t = 1..504) ----
    for (int w = 0; w < 21; ++w) {
        const int Wn = (w < 20) ? 24 : 7;        // next window's width (prefetch guard)
        float ynext = 1.0f;
        if (li < Wn) ynext = y[yrow + 1 + 24 * (w + 1) + li];

        const float ay = a * ycur;
        float Q = ay * frcp(sreg);               // c_t
        Q = fmaf(m1,  bperm(ad1,  Q), Q);        // 5-step scan, 1 bpermute + 1 fma each
        Q = fmaf(m2,  bperm(ad2,  Q), Q);
        Q = fmaf(m4,  bperm(ad4,  Q), Q);
        Q = fmaf(m8,  bperm(ad8,  Q), Q);
        Q = fmaf(m16, bperm(ad16, Q), Q);
        const float nl = fmaf(Pl, lev, Q);       // lev at t = 1+24w+li
        const float ns = fmaf(A, sreg, ay * frcp(nl));
        const float gv = flog2(nl);
        const float gsh = bperm(ad1, gv);        // unconditional (R5 fix)
        const float gp  = (li == 0) ? glev : gsh;

        if (li < 24) {
            const int t = 1 + 24 * w + li;
            lrow[t]      = nl;
            vrow[t + 24] = ns;
            drow[t - 1]  = (gv - gp) * LN2;
            sreg = ns;                           // seasonal slot update stays in-lane
        }
        lev  = bperm(adc, nl);                   // window carry (lane 23 of group)
        glev = bperm(adc, gv);
        ycur = ynext;
    }

    // ---- tail window: 7 steps (t = 505..511); scan depth 4 suffices ----
    {
        const float ay = a * ycur;
        float Q = ay * frcp(sreg);
        Q = fmaf(m1, bperm(ad1, Q), Q);
        Q = fmaf(m2, bperm(ad2, Q), Q);
        Q = fmaf(m4, bperm(ad4, Q), Q);
        const float nl = fmaf(Pl, lev, Q);
        const float ns = fmaf(A, sreg, ay * frcp(nl));
        const float gv = flog2(nl);
        const float gsh = bperm(ad1, gv);
        const float gp  = (li == 0) ? glev : gsh;
        if (li < 7) {
            const int t = 505 + li;
            lrow[t]      = nl;
            vrow[t + 24] = ns;
            drow[t - 1]  = (gv - gp) * LN2;
        }
    }
}

extern "C" void kernel_launch(void* const* d_in, const int* in_sizes, int n_in,
                              void* d_out, int out_size, void* d_ws, size_t ws_size,
                              hipStream_t stream)
{
    const float* y         = (const float*)d_in[0];
    const int*   idxs      = (const int*)d_in[1];
    const float* lev_sms   = (const float*)d_in[2];
    // d_in[3] (seas_sms) unused: reference derives both smoothings from lev_sms_p
    const float* init_seas = (const float*)d_in[4];
    const int n_series = in_sizes[1];

    float* levels = (float*)d_out;
    float* seasv  = levels + (size_t)n_series * NT;
    float* logdv  = seasv  + (size_t)n_series * SEA_STRIDE;

    // 8 series per 256-thread block (2 per wave) -> 4096 blocks, no LDS, no barriers
    es_fwd<<<n_series / 8, 256, 0, stream>>>(y, idxs, lev_sms, init_seas,
                                             levels, seasv, logdv);
}